// Round 5
// baseline (171.878 us; speedup 1.0000x reference)
//
#include <hip/hip_runtime.h>
#include <math.h>

// Problem: B=16, LQ=1024, LK=1024, DK=256, DV=256, fp32 in/out, mask int32.
// Identity: softmax_k(q_s + k_s with mask) == mask-weighted softmax of k_s alone
// (q_s cancels; masked entries are exactly -1e9 -> weight 0). query never read.
// k_s ~ N(0,256) => softmax mass concentrates in top ~30-60 keys; chunk-0
// (top-64) provably terminates ~all rows (e_64 ~ e^-26 * Z << 1e-5 * Z).
//
// R1: bitonic sort -> counting-sort select_kernel.
// R2 (FAILED, 218us): serial dependent scalar loads -> L2 latency chain.
// R3 (62us): lane-parallel metadata + register compaction; global V gather
//            latency-bound.
// R4 (50us): LDS-staged chunk-0 V walk. Counters: duration == hbm_bytes/BW at
//            only 1.1 TB/s -- the 64MB full-mask read lives in a kernel that
//            cannot saturate HBM (2 blocks/CU, barriers).
// R5: mask read factored into maskbit_kernel: pure streaming (4096 small
// blocks, no LDS, no barriers) reads mask coalesced once and emits ONE u64
// bitmask per row (mask at the batch's top-64 columns). attn metadata becomes
// 1 uniform 8B load; its HBM traffic drops ~3x. Rare chunks>=1 path gathers
// mask[row][k] per-lane directly.

#define NB     16
#define NL     1024     // LQ == LK
#define ND     256      // DK == DV
#define NBKT   128      // buckets of width 1.0 in log-space

// ---------------- Kernel A: ks[b,k] = dot(key[b,k,:], w) -----------------
__global__ __launch_bounds__(256)
void ks_kernel(const float* __restrict__ key, const float* __restrict__ w,
               float* __restrict__ ks) {
    int wid  = threadIdx.x >> 6;
    int lane = threadIdx.x & 63;
    int row  = blockIdx.x * 4 + wid;               // 0 .. NB*NL-1
    const float4* krow = (const float4*)(key + (size_t)row * ND);
    float4 kv = krow[lane];
    float4 wv = ((const float4*)w)[lane];
    float p = kv.x * wv.x + kv.y * wv.y + kv.z * wv.z + kv.w * wv.w;
    #pragma unroll
    for (int off = 32; off > 0; off >>= 1)
        p += __shfl_xor(p, off, 64);
    if (lane == 0) ks[row] = p;
}

// ------- Kernel B: per batch: max, e=exp(ks-m), counting sort by -------
// ------- bucket floor(m-v), exact suffix mass at chunk boundaries -------
__global__ __launch_bounds__(1024)
void select_kernel(const float* __restrict__ ks,
                   float2* __restrict__ pk, float* __restrict__ rem) {
    __shared__ float red[NL];      // max-reduce scratch
    __shared__ float se[NL];       // gathered e values (bucket order)
    __shared__ int   cnt[NBKT];    // histogram
    __shared__ int   cur[NBKT];    // scan -> scatter cursors
    __shared__ float csum[16];     // per-chunk sums
    const int b = blockIdx.x;
    const int t = threadIdx.x;
    const int lane = t & 63;
    const int wid  = t >> 6;

    float v = ks[b * NL + t];

    // block max
    red[t] = v;
    __syncthreads();
    for (int off = 512; off > 0; off >>= 1) {
        if (t < off) red[t] = fmaxf(red[t], red[t + off]);
        __syncthreads();
    }
    const float m = red[0];
    __syncthreads();

    const float e = __expf(v - m);          // e in (0,1]

    // histogram of bucket = clamp(floor(m - v), 0, NBKT-1)
    if (t < NBKT) cnt[t] = 0;
    __syncthreads();
    int bkt = (int)fminf(m - v, (float)(NBKT - 1));   // m - v >= 0
    atomicAdd(&cnt[bkt], 1);
    __syncthreads();

    // inclusive scan of cnt (Hillis-Steele over 128 entries)
    if (t < NBKT) cur[t] = cnt[t];
    __syncthreads();
    for (int off = 1; off < NBKT; off <<= 1) {
        int add = 0;
        if (t < NBKT && t >= off) add = cur[t - off];
        __syncthreads();
        if (t < NBKT) cur[t] += add;
        __syncthreads();
    }
    // exclusive prefix -> scatter cursor base
    if (t < NBKT) cur[t] -= cnt[t];
    __syncthreads();

    // scatter (bijective: every t gets a unique p in [0, NL))
    int p = atomicAdd(&cur[bkt], 1);
    se[p] = e;
    pk[b * NL + p] = make_float2(e, __int_as_float(t));
    __syncthreads();

    // per-chunk sums: wave w reduces chunk w (64 entries)
    float s = se[wid * 64 + lane];
    #pragma unroll
    for (int off = 32; off > 0; off >>= 1)
        s += __shfl_xor(s, off, 64);
    if (lane == 0) csum[wid] = s;
    __syncthreads();

    // suffix masses at the 16 boundary slots attn actually reads
    if (t == 0) {
        float run = 0.0f;
        for (int c = 15; c >= 0; --c) {
            rem[b * NL + c * 64 + 63] = run;
            run += csum[c];
        }
    }
}

// ------- Kernel B2: per row, bitmask of mask[row][.] at batch top-64 -------
// Pure streaming: 4 waves/block, 1 row/wave, coalesced 4KB mask-row read,
// no LDS arrays, no barriers. bit i of bmask[row] = (mask[row][k_i] != 0).
__global__ __launch_bounds__(256)
void maskbit_kernel(const int* __restrict__ mask, const float2* __restrict__ pk,
                    unsigned long long* __restrict__ bmask) {
    const int wid  = threadIdx.x >> 6;
    const int lane = threadIdx.x & 63;
    const int row  = blockIdx.x * 4 + wid;    // 0 .. NB*NL-1
    const int b    = row >> 10;

    // lane i holds the batch's top-i key index
    int k = __float_as_int(pk[(b << 10) + lane].y);

    // mask row -> 16 bits per lane: lane owns columns [lane*16, lane*16+16)
    const int4* mrow4 = (const int4*)(mask + (size_t)row * NL);
    unsigned int bits = 0;
    #pragma unroll
    for (int j = 0; j < 4; ++j) {
        int4 m = mrow4[lane * 4 + j];
        bits |= (m.x != 0 ? 1u : 0u) << (j * 4 + 0);
        bits |= (m.y != 0 ? 1u : 0u) << (j * 4 + 1);
        bits |= (m.z != 0 ? 1u : 0u) << (j * 4 + 2);
        bits |= (m.w != 0 ? 1u : 0u) << (j * 4 + 3);
    }

    // bit for column k lives in lane (k>>4), bit (k&15)
    unsigned int bk = (unsigned int)
        __builtin_amdgcn_ds_bpermute((k >> 4) << 2, (int)bits);
    bool mb = (bk >> (k & 15)) & 1u;
    unsigned long long bm = __ballot(mb);
    if (lane == 0) bmask[row] = bm;
}

// ---------------- Kernel C: out[b,q,:] = sum_k p * value[b,k,:] ----------
// 1024 threads = 16 waves = 16 q-rows (same batch). Chunk-0 V rows staged in
// LDS once per block; per-row metadata = 1 uniform u64 (bmask) + lane-parallel
// pk; walk reads ds_read_b128 with 4 independent accumulators.
__global__ __launch_bounds__(1024)
void attn_kernel(const float* __restrict__ value, const int* __restrict__ mask,
                 const float2* __restrict__ pk, const float* __restrict__ rem,
                 const unsigned long long* __restrict__ bmask,
                 float* __restrict__ out) {
    __shared__ float lds_V[64 * ND];          // 64 KB: chunk-0 value rows

    const int wid  = threadIdx.x >> 6;
    const int lane = threadIdx.x & 63;
    const int row  = blockIdx.x * 16 + wid;   // 0 .. NB*NL-1 (16 rows, same b)
    const int b    = row >> 10;
    const int base = b << 10;

    const float4* vbase = (const float4*)(value + ((size_t)b << 10) * ND);
    const float2* pk_g  = pk + base;

    // chunk-0 metadata, lane-parallel: lane i holds entry i's (e, k)
    float2 p0 = pk_g[lane];
    float e0 = p0.x;
    int   k0 = __float_as_int(p0.y);

    // per-row mask bits at top-64 columns: one wave-uniform 8B load
    const unsigned long long bm = bmask[row];

    // stage chunk-0 V rows: wave w stages slots 4w..4w+3 (coalesced 1KB each)
    #pragma unroll
    for (int j = 0; j < 4; ++j) {
        int s  = wid * 4 + j;
        int ks = __builtin_amdgcn_readlane(k0, s);
        ((float4*)lds_V)[s * 64 + lane] = vbase[(size_t)ks * 64 + lane];
    }

    __syncthreads();   // lds_V ready

    // ---- chunk 0: compact (e, slot) of active lanes to low lanes ----
    bool mb = (bm >> lane) & 1ull;
    int NA = __popcll(bm);
    unsigned int blo = (unsigned int)bm, bhi = (unsigned int)(bm >> 32);
    int cntA = __builtin_amdgcn_mbcnt_hi(bhi,
               __builtin_amdgcn_mbcnt_lo(blo, 0));
    int dest = mb ? cntA : (NA + (lane - cntA));
    int ec = __builtin_amdgcn_ds_permute(dest << 2, __float_as_int(e0));
    int sc = __builtin_amdgcn_ds_permute(dest << 2, lane);

    float4 a0 = make_float4(0.f, 0.f, 0.f, 0.f);
    float4 a1 = make_float4(0.f, 0.f, 0.f, 0.f);
    float4 a2 = make_float4(0.f, 0.f, 0.f, 0.f);
    float4 a3 = make_float4(0.f, 0.f, 0.f, 0.f);
    float Z = 0.0f;

    int i = 0;
    for (; i + 4 <= NA; i += 4) {
        int   s0 = __builtin_amdgcn_readlane(sc, i);
        int   s1 = __builtin_amdgcn_readlane(sc, i + 1);
        int   s2 = __builtin_amdgcn_readlane(sc, i + 2);
        int   s3 = __builtin_amdgcn_readlane(sc, i + 3);
        float w0 = __int_as_float(__builtin_amdgcn_readlane(ec, i));
        float w1 = __int_as_float(__builtin_amdgcn_readlane(ec, i + 1));
        float w2 = __int_as_float(__builtin_amdgcn_readlane(ec, i + 2));
        float w3 = __int_as_float(__builtin_amdgcn_readlane(ec, i + 3));
        float4 v0 = ((const float4*)lds_V)[s0 * 64 + lane];
        float4 v1 = ((const float4*)lds_V)[s1 * 64 + lane];
        float4 v2 = ((const float4*)lds_V)[s2 * 64 + lane];
        float4 v3 = ((const float4*)lds_V)[s3 * 64 + lane];
        Z += w0 + w1 + w2 + w3;
        a0.x += w0 * v0.x; a0.y += w0 * v0.y; a0.z += w0 * v0.z; a0.w += w0 * v0.w;
        a1.x += w1 * v1.x; a1.y += w1 * v1.y; a1.z += w1 * v1.z; a1.w += w1 * v1.w;
        a2.x += w2 * v2.x; a2.y += w2 * v2.y; a2.z += w2 * v2.z; a2.w += w2 * v2.w;
        a3.x += w3 * v3.x; a3.y += w3 * v3.y; a3.z += w3 * v3.z; a3.w += w3 * v3.w;
    }
    for (; i < NA; ++i) {
        int   s0 = __builtin_amdgcn_readlane(sc, i);
        float w0 = __int_as_float(__builtin_amdgcn_readlane(ec, i));
        float4 v0 = ((const float4*)lds_V)[s0 * 64 + lane];
        Z += w0;
        a0.x += w0 * v0.x; a0.y += w0 * v0.y; a0.z += w0 * v0.z; a0.w += w0 * v0.w;
    }

    float4 acc = make_float4(a0.x + a1.x + a2.x + a3.x,
                             a0.y + a1.y + a2.y + a3.y,
                             a0.z + a1.z + a2.z + a3.z,
                             a0.w + a1.w + a2.w + a3.w);
    bool done = (rem[base + 63] <= 1e-5f * Z);   // Z==0 -> rem>0 -> continue

    // ---- chunks 1..15 (provably almost never taken): global path ----
    const int* mrow = mask + (size_t)row * NL;
    for (int c = 1; c < 16 && !done; ++c) {
        float2 p = pk_g[c * 64 + lane];
        float e  = p.x;
        int   k  = __float_as_int(p.y);
        bool mb2 = (mrow[k] != 0);               // per-lane gather
        unsigned long long bm2 = __ballot(mb2);
        int NA2 = __popcll(bm2);
        if (NA2 > 0) {
            unsigned int lo2 = (unsigned int)bm2, hi2 = (unsigned int)(bm2 >> 32);
            int cnt2 = __builtin_amdgcn_mbcnt_hi(hi2,
                       __builtin_amdgcn_mbcnt_lo(lo2, 0));
            int d2 = mb2 ? cnt2 : (NA2 + (lane - cnt2));
            int ec2 = __builtin_amdgcn_ds_permute(d2 << 2, __float_as_int(e));
            int kc2 = __builtin_amdgcn_ds_permute(d2 << 2, k);
            #pragma unroll 4
            for (int t = 0; t < NA2; ++t) {
                float es  = __int_as_float(__builtin_amdgcn_readlane(ec2, t));
                int   ksv = __builtin_amdgcn_readlane(kc2, t);
                float4 v  = vbase[(size_t)ksv * 64 + lane];
                Z += es;
                acc.x += es * v.x; acc.y += es * v.y;
                acc.z += es * v.z; acc.w += es * v.w;
            }
        }
        done = (rem[base + c * 64 + 63] <= 1e-5f * Z);
    }

    float4* orow = (float4*)(out + (size_t)row * ND);
    if (Z > 0.0f) {
        float inv = 1.0f / Z;
        orow[lane] = make_float4(acc.x * inv, acc.y * inv, acc.z * inv, acc.w * inv);
    } else {
        // all-masked row: reference softmax over constant -1e9 -> uniform avg
        float4 s = make_float4(0.f, 0.f, 0.f, 0.f);
        for (int k = 0; k < NL; ++k) {
            float4 v = vbase[(size_t)k * 64 + lane];
            s.x += v.x; s.y += v.y; s.z += v.z; s.w += v.w;
        }
        const float inv = 1.0f / (float)NL;
        orow[lane] = make_float4(s.x * inv, s.y * inv, s.z * inv, s.w * inv);
    }
}

extern "C" void kernel_launch(void* const* d_in, const int* in_sizes, int n_in,
                              void* d_out, int out_size, void* d_ws, size_t ws_size,
                              hipStream_t stream) {
    // setup_inputs order: query, key, value, w, mask   (query unused!)
    const float* key   = (const float*)d_in[1];
    const float* value = (const float*)d_in[2];
    const float* w     = (const float*)d_in[3];
    const int*   mask  = (const int*)d_in[4];
    float*       outp  = (float*)d_out;

    float*  ks  = (float*)d_ws;                  // 16*1024 f32
    float2* pkb = (float2*)(ks + NB * NL);       // 16*1024 f32x2 (e, idx) bucket-desc
    float*  rem = (float*)(pkb + NB * NL);       // 16*1024 f32 suffix masses
    unsigned long long* bmask =
        (unsigned long long*)(rem + NB * NL);    // 16*1024 u64 top-64 mask bits

    ks_kernel     <<<NB * NL / 4, 256, 0, stream>>>(key, w, ks);
    select_kernel <<<NB, 1024, 0, stream>>>(ks, pkb, rem);
    maskbit_kernel<<<NB * NL / 4, 256, 0, stream>>>(mask, pkb, bmask);
    attn_kernel   <<<NB * NL / 16, 1024, 0, stream>>>(value, mask, pkb, rem, bmask, outp);
}

// Round 6
// 171.331 us; speedup vs baseline: 1.0032x; 1.0032x over previous
//
#include <hip/hip_runtime.h>
#include <math.h>

// Problem: B=16, LQ=1024, LK=1024, DK=256, DV=256, fp32 in/out, mask int32.
// Identity: softmax_k(q_s + k_s with mask) == mask-weighted softmax of k_s alone
// (q_s cancels; masked entries are exactly -1e9 -> weight 0). query never read.
// k_s ~ N(0,256) => softmax mass concentrates in top ~30-60 keys; chunk-0
// (top-64) provably terminates ~all rows (e_64 ~ e^-26 * Z << 1e-5 * Z).
//
// R1: bitonic sort -> counting-sort select_kernel.
// R2 (FAILED, 218us): serial dependent scalar loads -> L2 latency chain.
// R3 (62us): lane-parallel metadata, but rolled global walk = latency-bound.
// R4 (50us): LDS-staged walk; mask stream stuck in a 1.1 TB/s kernel.
// R5 (~neutral): mask factored into maskbit_kernel; launch + round-trip ate it.
// R6: (a) maskbit folded back into a high-occupancy fused attn (4 waves/block,
// no LDS arrays, no barriers, manual 4x-unrolled walk with 4 independent
// accumulators -> ~128 loads in flight/CU); (b) mask row read fully coalesced
// (lane + 64*j int4 pattern, was stride-64B with holes); (c) select_kernel
// rebuilt at 256 threads: wave-shuffle max, single-wave shuffle-scan of 128
// buckets, 5 cheap barriers (was ~25 heavy ones).

#define NB     16
#define NL     1024     // LQ == LK
#define ND     256      // DK == DV
#define NBKT   128      // buckets of width 1.0 in log-space

// ---------------- Kernel A: ks[b,k] = dot(key[b,k,:], w) -----------------
__global__ __launch_bounds__(256)
void ks_kernel(const float* __restrict__ key, const float* __restrict__ w,
               float* __restrict__ ks) {
    int wid  = threadIdx.x >> 6;
    int lane = threadIdx.x & 63;
    int row  = blockIdx.x * 4 + wid;               // 0 .. NB*NL-1
    const float4* krow = (const float4*)(key + (size_t)row * ND);
    float4 kv = krow[lane];
    float4 wv = ((const float4*)w)[lane];
    float p = kv.x * wv.x + kv.y * wv.y + kv.z * wv.z + kv.w * wv.w;
    #pragma unroll
    for (int off = 32; off > 0; off >>= 1)
        p += __shfl_xor(p, off, 64);
    if (lane == 0) ks[row] = p;
}

// ------- Kernel B: per batch: max, e=exp(ks-m), counting sort by -------
// ------- bucket floor(m-v), exact suffix mass at chunk boundaries -------
// 256 threads (4 waves), 4 entries/thread. Order within a bucket arbitrary;
// attn breaks on the EXACT suffix mass rem[] of the actual gathered order.
__global__ __launch_bounds__(256)
void select_kernel(const float* __restrict__ ks,
                   float2* __restrict__ pk, float* __restrict__ rem) {
    __shared__ float se[NL];       // gathered e values (bucket order)
    __shared__ int   cnt[NBKT];    // histogram
    __shared__ int   cur[NBKT];    // scan -> scatter cursors
    __shared__ float wred[4];      // per-wave max
    __shared__ float csum[16];     // per-chunk sums
    const int b    = blockIdx.x;
    const int t    = threadIdx.x;
    const int lane = t & 63;
    const int wid  = t >> 6;
    const float* ksb = ks + b * NL;

    if (t < NBKT) cnt[t] = 0;

    // 4 entries per thread, coalesced (stride 256)
    float v0 = ksb[t], v1 = ksb[t + 256], v2 = ksb[t + 512], v3 = ksb[t + 768];

    // block max: thread max4 -> wave shuffle reduce -> 4-way LDS combine
    float mx = fmaxf(fmaxf(v0, v1), fmaxf(v2, v3));
    #pragma unroll
    for (int off = 32; off > 0; off >>= 1)
        mx = fmaxf(mx, __shfl_xor(mx, off, 64));
    if (lane == 0) wred[wid] = mx;
    __syncthreads();                                        // #1 (also covers cnt=0)
    const float m = fmaxf(fmaxf(wred[0], wred[1]), fmaxf(wred[2], wred[3]));

    float e0 = __expf(v0 - m), e1 = __expf(v1 - m);
    float e2 = __expf(v2 - m), e3 = __expf(v3 - m);
    int b0 = (int)fminf(m - v0, (float)(NBKT - 1));
    int b1 = (int)fminf(m - v1, (float)(NBKT - 1));
    int b2 = (int)fminf(m - v2, (float)(NBKT - 1));
    int b3 = (int)fminf(m - v3, (float)(NBKT - 1));
    atomicAdd(&cnt[b0], 1); atomicAdd(&cnt[b1], 1);
    atomicAdd(&cnt[b2], 1); atomicAdd(&cnt[b3], 1);
    __syncthreads();                                        // #2

    // exclusive scan of cnt[128] by wave 0 via shuffles (no barriers inside)
    if (wid == 0) {
        int a  = cnt[lane];
        int b2v = cnt[lane + 64];
        int sa = a, sb = b2v;
        #pragma unroll
        for (int d = 1; d < 64; d <<= 1) {
            int na = __shfl_up(sa, d, 64);
            int nb = __shfl_up(sb, d, 64);
            if (lane >= d) { sa += na; sb += nb; }
        }
        int tot = __shfl(sa, 63, 64);
        sb += tot;
        cur[lane]      = sa - a;
        cur[lane + 64] = sb - b2v;
    }
    __syncthreads();                                        // #3

    // scatter (bijective: every entry gets a unique p in [0, NL))
    int p0 = atomicAdd(&cur[b0], 1);
    int p1 = atomicAdd(&cur[b1], 1);
    int p2 = atomicAdd(&cur[b2], 1);
    int p3 = atomicAdd(&cur[b3], 1);
    se[p0] = e0; pk[b * NL + p0] = make_float2(e0, __int_as_float(t));
    se[p1] = e1; pk[b * NL + p1] = make_float2(e1, __int_as_float(t + 256));
    se[p2] = e2; pk[b * NL + p2] = make_float2(e2, __int_as_float(t + 512));
    se[p3] = e3; pk[b * NL + p3] = make_float2(e3, __int_as_float(t + 768));
    __syncthreads();                                        // #4

    // per-chunk sums: wave w reduces chunks 4w..4w+3
    #pragma unroll
    for (int cc = 0; cc < 4; ++cc) {
        int chunk = wid * 4 + cc;
        float s = se[chunk * 64 + lane];
        #pragma unroll
        for (int off = 32; off > 0; off >>= 1)
            s += __shfl_xor(s, off, 64);
        if (lane == 0) csum[chunk] = s;
    }
    __syncthreads();                                        // #5

    // suffix masses at the 16 boundary slots attn actually reads
    if (t == 0) {
        float run = 0.0f;
        for (int c = 15; c >= 0; --c) {
            rem[b * NL + c * 64 + 63] = run;
            run += csum[c];
        }
    }
}

// ---------------- Kernel C: out[b,q,:] = sum_k p * value[b,k,:] ----------
// Fused mask+walk. 256 threads = 4 waves = 4 q-rows; grid 4096; no LDS
// arrays, no barriers -> high occupancy. Per row: coalesced 4KB mask read
// (lane + 64*j int4 pattern), bpermute bit resolve, ballot, bijective
// ds_permute compaction of (e,k), then a manually 4x-unrolled global V walk
// with 4 independent accumulators (loads independent -> pipelined; V top-64
// rows are L2-hot, 64KB/batch).
__global__ __launch_bounds__(256)
void attn_kernel(const float* __restrict__ value, const int* __restrict__ mask,
                 const float2* __restrict__ pk, const float* __restrict__ rem,
                 float* __restrict__ out) {
    const int wid  = threadIdx.x >> 6;
    const int lane = threadIdx.x & 63;
    const int row  = blockIdx.x * 4 + wid;    // 0 .. NB*NL-1
    const int b    = row >> 10;
    const int base = b << 10;

    const float4* vbase = (const float4*)(value + ((size_t)b << 10) * ND);
    const float2* pk_g  = pk + base;

    // chunk-0 metadata, lane-parallel: lane i holds entry i's (e, k)
    float2 p0 = pk_g[lane];
    float e0 = p0.x;
    int   k0 = __float_as_int(p0.y);

    // mask row, fully coalesced: load j covers columns 256j + 4*lane + (0..3)
    // lane's 16 bits: bit (4j + c) = column 256j + 4*lane + c
    const int4* mrow4 = (const int4*)(mask + (size_t)row * NL);
    unsigned int bits = 0;
    #pragma unroll
    for (int j = 0; j < 4; ++j) {
        int4 mm = mrow4[lane + 64 * j];
        bits |= (mm.x != 0 ? 1u : 0u) << (j * 4 + 0);
        bits |= (mm.y != 0 ? 1u : 0u) << (j * 4 + 1);
        bits |= (mm.z != 0 ? 1u : 0u) << (j * 4 + 2);
        bits |= (mm.w != 0 ? 1u : 0u) << (j * 4 + 3);
    }

    // bit for column k: lane (k>>2)&63, bit (k&3) + 4*(k>>8)
    unsigned int bk = (unsigned int)
        __builtin_amdgcn_ds_bpermute(((k0 >> 2) & 63) << 2, (int)bits);
    bool mb = (bk >> ((k0 & 3) + ((k0 >> 8) << 2))) & 1u;

    unsigned long long bm = __ballot(mb);
    int NA = __popcll(bm);
    unsigned int blo = (unsigned int)bm, bhi = (unsigned int)(bm >> 32);
    int cntA = __builtin_amdgcn_mbcnt_hi(bhi,
               __builtin_amdgcn_mbcnt_lo(blo, 0));
    int dest = mb ? cntA : (NA + (lane - cntA));
    int ec = __builtin_amdgcn_ds_permute(dest << 2, __float_as_int(e0));
    int kc = __builtin_amdgcn_ds_permute(dest << 2, k0);

    float4 a0 = make_float4(0.f, 0.f, 0.f, 0.f);
    float4 a1 = make_float4(0.f, 0.f, 0.f, 0.f);
    float4 a2 = make_float4(0.f, 0.f, 0.f, 0.f);
    float4 a3 = make_float4(0.f, 0.f, 0.f, 0.f);
    float Z = 0.0f;

    int i = 0;
    for (; i + 4 <= NA; i += 4) {
        int   s0 = __builtin_amdgcn_readlane(kc, i);
        int   s1 = __builtin_amdgcn_readlane(kc, i + 1);
        int   s2 = __builtin_amdgcn_readlane(kc, i + 2);
        int   s3 = __builtin_amdgcn_readlane(kc, i + 3);
        float w0 = __int_as_float(__builtin_amdgcn_readlane(ec, i));
        float w1 = __int_as_float(__builtin_amdgcn_readlane(ec, i + 1));
        float w2 = __int_as_float(__builtin_amdgcn_readlane(ec, i + 2));
        float w3 = __int_as_float(__builtin_amdgcn_readlane(ec, i + 3));
        float4 v0 = vbase[(size_t)s0 * 64 + lane];
        float4 v1 = vbase[(size_t)s1 * 64 + lane];
        float4 v2 = vbase[(size_t)s2 * 64 + lane];
        float4 v3 = vbase[(size_t)s3 * 64 + lane];
        Z += w0 + w1 + w2 + w3;
        a0.x += w0 * v0.x; a0.y += w0 * v0.y; a0.z += w0 * v0.z; a0.w += w0 * v0.w;
        a1.x += w1 * v1.x; a1.y += w1 * v1.y; a1.z += w1 * v1.z; a1.w += w1 * v1.w;
        a2.x += w2 * v2.x; a2.y += w2 * v2.y; a2.z += w2 * v2.z; a2.w += w2 * v2.w;
        a3.x += w3 * v3.x; a3.y += w3 * v3.y; a3.z += w3 * v3.z; a3.w += w3 * v3.w;
    }
    for (; i < NA; ++i) {
        int   s0 = __builtin_amdgcn_readlane(kc, i);
        float w0 = __int_as_float(__builtin_amdgcn_readlane(ec, i));
        float4 v0 = vbase[(size_t)s0 * 64 + lane];
        Z += w0;
        a0.x += w0 * v0.x; a0.y += w0 * v0.y; a0.z += w0 * v0.z; a0.w += w0 * v0.w;
    }

    float4 acc = make_float4(a0.x + a1.x + a2.x + a3.x,
                             a0.y + a1.y + a2.y + a3.y,
                             a0.z + a1.z + a2.z + a3.z,
                             a0.w + a1.w + a2.w + a3.w);
    bool done = (rem[base + 63] <= 1e-5f * Z);   // Z==0 -> rem>0 -> continue

    // ---- chunks 1..15 (provably almost never taken): per-lane mask gather ----
    const int* mrow = mask + (size_t)row * NL;
    for (int c = 1; c < 16 && !done; ++c) {
        float2 p = pk_g[c * 64 + lane];
        float e  = p.x;
        int   k  = __float_as_int(p.y);
        bool mb2 = (mrow[k] != 0);
        unsigned long long bm2 = __ballot(mb2);
        int NA2 = __popcll(bm2);
        if (NA2 > 0) {
            unsigned int lo2 = (unsigned int)bm2, hi2 = (unsigned int)(bm2 >> 32);
            int cnt2 = __builtin_amdgcn_mbcnt_hi(hi2,
                       __builtin_amdgcn_mbcnt_lo(lo2, 0));
            int d2 = mb2 ? cnt2 : (NA2 + (lane - cnt2));
            int ec2 = __builtin_amdgcn_ds_permute(d2 << 2, __float_as_int(e));
            int kc2 = __builtin_amdgcn_ds_permute(d2 << 2, k);
            #pragma unroll 4
            for (int t = 0; t < NA2; ++t) {
                float es  = __int_as_float(__builtin_amdgcn_readlane(ec2, t));
                int   ksv = __builtin_amdgcn_readlane(kc2, t);
                float4 v  = vbase[(size_t)ksv * 64 + lane];
                Z += es;
                acc.x += es * v.x; acc.y += es * v.y;
                acc.z += es * v.z; acc.w += es * v.w;
            }
        }
        done = (rem[base + c * 64 + 63] <= 1e-5f * Z);
    }

    float4* orow = (float4*)(out + (size_t)row * ND);
    if (Z > 0.0f) {
        float inv = 1.0f / Z;
        orow[lane] = make_float4(acc.x * inv, acc.y * inv, acc.z * inv, acc.w * inv);
    } else {
        // all-masked row: reference softmax over constant -1e9 -> uniform avg
        float4 s = make_float4(0.f, 0.f, 0.f, 0.f);
        for (int k = 0; k < NL; ++k) {
            float4 v = vbase[(size_t)k * 64 + lane];
            s.x += v.x; s.y += v.y; s.z += v.z; s.w += v.w;
        }
        const float inv = 1.0f / (float)NL;
        orow[lane] = make_float4(s.x * inv, s.y * inv, s.z * inv, s.w * inv);
    }
}

extern "C" void kernel_launch(void* const* d_in, const int* in_sizes, int n_in,
                              void* d_out, int out_size, void* d_ws, size_t ws_size,
                              hipStream_t stream) {
    // setup_inputs order: query, key, value, w, mask   (query unused!)
    const float* key   = (const float*)d_in[1];
    const float* value = (const float*)d_in[2];
    const float* w     = (const float*)d_in[3];
    const int*   mask  = (const int*)d_in[4];
    float*       outp  = (float*)d_out;

    float*  ks  = (float*)d_ws;                  // 16*1024 f32
    float2* pkb = (float2*)(ks + NB * NL);       // 16*1024 f32x2 (e, idx) bucket-desc
    float*  rem = (float*)(pkb + NB * NL);       // 16*1024 f32 suffix masses

    ks_kernel    <<<NB * NL / 4, 256, 0, stream>>>(key, w, ks);
    select_kernel<<<NB, 256, 0, stream>>>(ks, pkb, rem);
    attn_kernel  <<<NB * NL / 4, 256, 0, stream>>>(value, mask, pkb, rem, outp);
}